// Round 1
// baseline (110.339 us; speedup 1.0000x reference)
//
#include <hip/hip_runtime.h>

#define HID 8192
#define BATCH 512
#define NIN 16
#define RK 8
#define NOUT 4

// fast tanh via hardware exp + rcp: tanh(x) = 1 - 2/(exp(2x)+1)
// exact at +-inf limits; ~1e-6 rel error, far inside threshold.
__device__ __forceinline__ float ftanh(float x) {
    float e = __expf(2.0f * x);
    return 1.0f - 2.0f * __builtin_amdgcn_rcpf(e + 1.0f);
}

// Kernel 1: u[b,r] = sum_j tanh(h[b,j]) * R[r,j], pre-scaled by 0.1/H.
// Grid: (jt=8 tiles of 1024 j) x (bt=64 tiles of 8 batches), 256 threads.
// R fragment (8 rows x float4) lives in registers across the 8-batch loop
// so R is fetched from L2 once per 8 batches, not once per batch.
__global__ __launch_bounds__(256) void k_uproj(
    const float* __restrict__ h, const float* __restrict__ R,
    float* __restrict__ upart /* [8][BATCH][8] */) {
    const int jt = blockIdx.x;   // 0..7
    const int bt = blockIdx.y;   // 0..63
    const int t  = threadIdx.x;  // 0..255
    const int j  = jt * 1024 + t * 4;

    float4 Rr[RK];
#pragma unroll
    for (int r = 0; r < RK; ++r)
        Rr[r] = *reinterpret_cast<const float4*>(&R[r * HID + j]);

    __shared__ float red[4][RK];
    const float sc = 0.1f / (float)HID;

    for (int bi = 0; bi < 8; ++bi) {
        const int b = bt * 8 + bi;
        float4 hv = *reinterpret_cast<const float4*>(&h[(size_t)b * HID + j]);
        float tx = ftanh(hv.x) * sc;
        float ty = ftanh(hv.y) * sc;
        float tz = ftanh(hv.z) * sc;
        float tw = ftanh(hv.w) * sc;
        float acc[RK];
#pragma unroll
        for (int r = 0; r < RK; ++r)
            acc[r] = tx * Rr[r].x + ty * Rr[r].y + tz * Rr[r].z + tw * Rr[r].w;

        // wave64 butterfly reduce each of the 8 accumulators
#pragma unroll
        for (int r = 0; r < RK; ++r) {
            float v = acc[r];
#pragma unroll
            for (int off = 32; off > 0; off >>= 1)
                v += __shfl_down(v, off, 64);
            acc[r] = v;
        }
        const int wave = t >> 6;
        if ((t & 63) == 0) {
#pragma unroll
            for (int r = 0; r < RK; ++r) red[wave][r] = acc[r];
        }
        __syncthreads();
        if (t < RK) {
            float s = red[0][t] + red[1][t] + red[2][t] + red[3][t];
            upart[((size_t)jt * BATCH + b) * RK + t] = s;
        }
        __syncthreads();  // protect LDS before next batch iteration
    }
}

// Kernel 2: new_h[b,j] = 0.9*h + sum_r us[b,r]*L[j,r] + sum_i (0.1*in[b,i])*W_in[j,i]
// plus readout partials o[b,k] += tanh(new_h)*W_out[k,j]/H.
// Grid: (jt=16 tiles of 512 j) x (bt=64 tiles of 8 batches), 256 threads, 2 j/thread.
// Per-thread weights (16 L + 32 W_in + 8 W_out floats) in registers, reused
// over the 8-batch loop. us/in staged in LDS, read as float4 broadcasts.
__global__ __launch_bounds__(256) void k_step(
    const float* __restrict__ h, const float* __restrict__ input,
    const float* __restrict__ W_in, const float* __restrict__ L,
    const float* __restrict__ W_out, const float* __restrict__ upart,
    float* __restrict__ out /* d_out base */,
    float* __restrict__ opart /* [16][BATCH][4] */) {
    const int jt = blockIdx.x;   // 0..15
    const int bt = blockIdx.y;   // 0..63
    const int t  = threadIdx.x;  // 0..255
    const int j0 = jt * 512 + t * 2;

    __shared__ __align__(16) float us_lds[64];    // [8 batches][8 r]
    __shared__ __align__(16) float in_lds[128];   // [8 batches][16 i], pre-scaled by 0.1
    __shared__ float ored[4][32];

    if (t < 64) {
        float s = 0.f;
#pragma unroll
        for (int p = 0; p < 8; ++p)
            s += upart[(size_t)p * (BATCH * RK) + bt * 64 + t];
        us_lds[t] = s;
    } else if (t < 192) {
        const int tl = t - 64;
        in_lds[tl] = input[bt * 128 + tl] * 0.1f;
    }

    // preload per-thread weight fragments (coalesced: lane-consecutive j)
    float Lw[2][RK], Ww[2][NIN], Wo[2][NOUT];
#pragma unroll
    for (int jj = 0; jj < 2; ++jj) {
        const int j = j0 + jj;
        float4 a = *reinterpret_cast<const float4*>(&L[j * RK]);
        float4 b4 = *reinterpret_cast<const float4*>(&L[j * RK + 4]);
        Lw[jj][0] = a.x; Lw[jj][1] = a.y; Lw[jj][2] = a.z; Lw[jj][3] = a.w;
        Lw[jj][4] = b4.x; Lw[jj][5] = b4.y; Lw[jj][6] = b4.z; Lw[jj][7] = b4.w;
#pragma unroll
        for (int q = 0; q < 4; ++q) {
            float4 w = *reinterpret_cast<const float4*>(&W_in[j * NIN + q * 4]);
            Ww[jj][q * 4 + 0] = w.x; Ww[jj][q * 4 + 1] = w.y;
            Ww[jj][q * 4 + 2] = w.z; Ww[jj][q * 4 + 3] = w.w;
        }
#pragma unroll
        for (int k = 0; k < NOUT; ++k)
            Wo[jj][k] = W_out[(size_t)k * HID + j] * (1.0f / (float)HID);
    }
    __syncthreads();

    float oacc[8][NOUT];
#pragma unroll
    for (int bi = 0; bi < 8; ++bi)
#pragma unroll
        for (int k = 0; k < NOUT; ++k) oacc[bi][k] = 0.f;

    for (int bi = 0; bi < 8; ++bi) {
        const int b = bt * 8 + bi;
        float2 hv = *reinterpret_cast<const float2*>(&h[(size_t)b * HID + j0]);
        float4 u0 = *reinterpret_cast<const float4*>(&us_lds[bi * 8]);
        float4 u1 = *reinterpret_cast<const float4*>(&us_lds[bi * 8 + 4]);
        float4 i0 = *reinterpret_cast<const float4*>(&in_lds[bi * 16]);
        float4 i1 = *reinterpret_cast<const float4*>(&in_lds[bi * 16 + 4]);
        float4 i2 = *reinterpret_cast<const float4*>(&in_lds[bi * 16 + 8]);
        float4 i3 = *reinterpret_cast<const float4*>(&in_lds[bi * 16 + 12]);

        float nh[2];
        float hvv[2] = {hv.x, hv.y};
#pragma unroll
        for (int jj = 0; jj < 2; ++jj) {
            // split into independent FMA chains for ILP
            float s0 = u0.x * Lw[jj][0] + u0.y * Lw[jj][1] + u0.z * Lw[jj][2] + u0.w * Lw[jj][3];
            float s1 = u1.x * Lw[jj][4] + u1.y * Lw[jj][5] + u1.z * Lw[jj][6] + u1.w * Lw[jj][7];
            float s2 = i0.x * Ww[jj][0] + i0.y * Ww[jj][1] + i0.z * Ww[jj][2] + i0.w * Ww[jj][3]
                     + i1.x * Ww[jj][4] + i1.y * Ww[jj][5] + i1.z * Ww[jj][6] + i1.w * Ww[jj][7];
            float s3 = i2.x * Ww[jj][8] + i2.y * Ww[jj][9] + i2.z * Ww[jj][10] + i2.w * Ww[jj][11]
                     + i3.x * Ww[jj][12] + i3.y * Ww[jj][13] + i3.z * Ww[jj][14] + i3.w * Ww[jj][15];
            nh[jj] = 0.9f * hvv[jj] + ((s0 + s1) + (s2 + s3));
        }
        *reinterpret_cast<float2*>(&out[2048 + (size_t)b * HID + j0]) =
            make_float2(nh[0], nh[1]);

        float th0 = ftanh(nh[0]);
        float th1 = ftanh(nh[1]);
#pragma unroll
        for (int k = 0; k < NOUT; ++k)
            oacc[bi][k] += th0 * Wo[0][k] + th1 * Wo[1][k];
    }

    // end-of-kernel readout reduction: wave butterfly -> LDS -> one store
    const int wave = t >> 6, lane = t & 63;
#pragma unroll
    for (int bi = 0; bi < 8; ++bi) {
#pragma unroll
        for (int k = 0; k < NOUT; ++k) {
            float v = oacc[bi][k];
#pragma unroll
            for (int off = 32; off > 0; off >>= 1)
                v += __shfl_down(v, off, 64);
            if (lane == 0) ored[wave][bi * 4 + k] = v;
        }
    }
    __syncthreads();
    if (t < 32) {
        float s = ored[0][t] + ored[1][t] + ored[2][t] + ored[3][t];
        opart[(size_t)jt * (BATCH * NOUT) + bt * 32 + t] = s;
    }
}

// Kernel 3: fold 16 j-tile partials into d_out[0:2048]
__global__ __launch_bounds__(256) void k_out(
    const float* __restrict__ opart, float* __restrict__ out) {
    const int t = blockIdx.x * 256 + threadIdx.x;  // 0..2047
    float s = 0.f;
#pragma unroll
    for (int p = 0; p < 16; ++p)
        s += opart[(size_t)p * 2048 + t];
    out[t] = s;
}

extern "C" void kernel_launch(void* const* d_in, const int* in_sizes, int n_in,
                              void* d_out, int out_size, void* d_ws, size_t ws_size,
                              hipStream_t stream) {
    const float* input = (const float*)d_in[0];   // [512,16]
    const float* hst   = (const float*)d_in[1];   // [512,8192]
    const float* W_in  = (const float*)d_in[2];   // [8192,16]
    const float* L     = (const float*)d_in[3];   // [8192,8]
    const float* R     = (const float*)d_in[4];   // [8,8192]
    const float* W_out = (const float*)d_in[5];   // [4,8192]
    float* out = (float*)d_out;                   // [2048 output | 512*8192 new_hidden]

    float* upart = (float*)d_ws;                  // 8*512*8   = 32768 floats (128 KB)
    float* opart = upart + 8 * BATCH * RK;        // 16*512*4  = 32768 floats (128 KB)

    k_uproj<<<dim3(8, 64), 256, 0, stream>>>(hst, R, upart);
    k_step<<<dim3(16, 64), 256, 0, stream>>>(hst, input, W_in, L, W_out, upart, out, opart);
    k_out<<<8, 256, 0, stream>>>(opart, out);
}

// Round 2
// 96.600 us; speedup vs baseline: 1.1422x; 1.1422x over previous
//
#include <hip/hip_runtime.h>

#define HID 8192
#define BATCH 512
#define NIN 16
#define RK 8
#define NOUT 4

// fast tanh via hardware exp + rcp: tanh(x) = 1 - 2/(exp(2x)+1)
__device__ __forceinline__ float ftanh(float x) {
    float e = __expf(2.0f * x);
    return 1.0f - 2.0f * __builtin_amdgcn_rcpf(e + 1.0f);
}

// wave64 sum via DPP (VALU pipe only — no LDS traffic). Result valid in lane 63.
// row_shr 1/2/4/8 builds 16-lane row sums in lanes 15/31/47/63;
// row_bcast:15 merges row pairs, row_bcast:31 merges the halves.
__device__ __forceinline__ float wave_sum_dpp(float v) {
    int x;
    x = __builtin_amdgcn_update_dpp(0, __float_as_int(v), 0x111, 0xf, 0xf, true); v += __int_as_float(x);
    x = __builtin_amdgcn_update_dpp(0, __float_as_int(v), 0x112, 0xf, 0xf, true); v += __int_as_float(x);
    x = __builtin_amdgcn_update_dpp(0, __float_as_int(v), 0x114, 0xf, 0xf, true); v += __int_as_float(x);
    x = __builtin_amdgcn_update_dpp(0, __float_as_int(v), 0x118, 0xf, 0xf, true); v += __int_as_float(x);
    x = __builtin_amdgcn_update_dpp(0, __float_as_int(v), 0x142, 0xf, 0xf, true); v += __int_as_float(x);
    x = __builtin_amdgcn_update_dpp(0, __float_as_int(v), 0x143, 0xf, 0xf, true); v += __int_as_float(x);
    return v;
}

// Kernel 1: u[b,r] = sum_j tanh(h[b,j]) * R[r,j], pre-scaled by 0.1/H.
// Grid: (jt=8 tiles of 1024 j) x (bt=128 tiles of 4 batches), 256 threads.
// Barrier-free batch loop: acc[4][8] in registers, h loads pipeline freely.
// One DPP reduction phase + one barrier at the end.
__global__ __launch_bounds__(256) void k_uproj(
    const float* __restrict__ h, const float* __restrict__ R,
    float* __restrict__ upart /* [8][BATCH][8] */) {
    const int jt = blockIdx.x;   // 0..7
    const int bt = blockIdx.y;   // 0..127
    const int t  = threadIdx.x;  // 0..255
    const int j  = jt * 1024 + t * 4;

    float4 Rr[RK];
#pragma unroll
    for (int r = 0; r < RK; ++r)
        Rr[r] = *reinterpret_cast<const float4*>(&R[r * HID + j]);

    const float sc = 0.1f / (float)HID;
    float acc[4][RK];
#pragma unroll
    for (int bi = 0; bi < 4; ++bi)
#pragma unroll
        for (int r = 0; r < RK; ++r) acc[bi][r] = 0.f;

#pragma unroll
    for (int bi = 0; bi < 4; ++bi) {
        const int b = bt * 4 + bi;
        float4 hv = *reinterpret_cast<const float4*>(&h[(size_t)b * HID + j]);
        float tx = ftanh(hv.x) * sc;
        float ty = ftanh(hv.y) * sc;
        float tz = ftanh(hv.z) * sc;
        float tw = ftanh(hv.w) * sc;
#pragma unroll
        for (int r = 0; r < RK; ++r)
            acc[bi][r] = tx * Rr[r].x + ty * Rr[r].y + tz * Rr[r].z + tw * Rr[r].w;
    }

    __shared__ float red[4][32];
    const int wave = t >> 6, lane = t & 63;
#pragma unroll
    for (int bi = 0; bi < 4; ++bi)
#pragma unroll
        for (int r = 0; r < RK; ++r) {
            float s = wave_sum_dpp(acc[bi][r]);
            if (lane == 63) red[wave][bi * RK + r] = s;
        }
    __syncthreads();
    if (t < 32) {
        float s = red[0][t] + red[1][t] + red[2][t] + red[3][t];
        const int b = bt * 4 + (t >> 3);
        upart[((size_t)jt * BATCH + b) * RK + (t & 7)] = s;
    }
}

// Kernel 2: new_h[b,j] = 0.9*h + sum_r us[b,r]*L[j,r] + sum_i (0.1*in[b,i])*W_in[j,i]
// plus readout partials (DPP-reduced at kernel end).
// Grid: (jt=16 tiles of 512 j) x (bt=64 tiles of 8 batches), 256 threads, 2 j/thread.
__global__ __launch_bounds__(256) void k_step(
    const float* __restrict__ h, const float* __restrict__ input,
    const float* __restrict__ W_in, const float* __restrict__ L,
    const float* __restrict__ W_out, const float* __restrict__ upart,
    float* __restrict__ out /* d_out base */,
    float* __restrict__ opart /* [16][BATCH][4] */) {
    const int jt = blockIdx.x;   // 0..15
    const int bt = blockIdx.y;   // 0..63
    const int t  = threadIdx.x;  // 0..255
    const int j0 = jt * 512 + t * 2;

    __shared__ __align__(16) float us_lds[64];    // [8 batches][8 r]
    __shared__ __align__(16) float in_lds[128];   // [8 batches][16 i], pre-scaled by 0.1
    __shared__ float ored[4][32];

    if (t < 64) {
        float s = 0.f;
#pragma unroll
        for (int p = 0; p < 8; ++p)
            s += upart[(size_t)p * (BATCH * RK) + bt * 64 + t];
        us_lds[t] = s;
    } else if (t < 192) {
        const int tl = t - 64;
        in_lds[tl] = input[bt * 128 + tl] * 0.1f;
    }

    // per-thread weight fragments in registers, reused across the 8-batch loop
    float Lw[2][RK], Ww[2][NIN], Wo[2][NOUT];
#pragma unroll
    for (int jj = 0; jj < 2; ++jj) {
        const int j = j0 + jj;
        float4 a = *reinterpret_cast<const float4*>(&L[j * RK]);
        float4 b4 = *reinterpret_cast<const float4*>(&L[j * RK + 4]);
        Lw[jj][0] = a.x; Lw[jj][1] = a.y; Lw[jj][2] = a.z; Lw[jj][3] = a.w;
        Lw[jj][4] = b4.x; Lw[jj][5] = b4.y; Lw[jj][6] = b4.z; Lw[jj][7] = b4.w;
#pragma unroll
        for (int q = 0; q < 4; ++q) {
            float4 w = *reinterpret_cast<const float4*>(&W_in[j * NIN + q * 4]);
            Ww[jj][q * 4 + 0] = w.x; Ww[jj][q * 4 + 1] = w.y;
            Ww[jj][q * 4 + 2] = w.z; Ww[jj][q * 4 + 3] = w.w;
        }
#pragma unroll
        for (int k = 0; k < NOUT; ++k)
            Wo[jj][k] = W_out[(size_t)k * HID + j] * (1.0f / (float)HID);
    }
    __syncthreads();

    float oacc[8][NOUT];
#pragma unroll
    for (int bi = 0; bi < 8; ++bi)
#pragma unroll
        for (int k = 0; k < NOUT; ++k) oacc[bi][k] = 0.f;

#pragma unroll
    for (int bi = 0; bi < 8; ++bi) {
        const int b = bt * 8 + bi;
        float2 hv = *reinterpret_cast<const float2*>(&h[(size_t)b * HID + j0]);
        float4 u0 = *reinterpret_cast<const float4*>(&us_lds[bi * 8]);
        float4 u1 = *reinterpret_cast<const float4*>(&us_lds[bi * 8 + 4]);
        float4 i0 = *reinterpret_cast<const float4*>(&in_lds[bi * 16]);
        float4 i1 = *reinterpret_cast<const float4*>(&in_lds[bi * 16 + 4]);
        float4 i2 = *reinterpret_cast<const float4*>(&in_lds[bi * 16 + 8]);
        float4 i3 = *reinterpret_cast<const float4*>(&in_lds[bi * 16 + 12]);

        float nh[2];
        float hvv[2] = {hv.x, hv.y};
#pragma unroll
        for (int jj = 0; jj < 2; ++jj) {
            float s0 = u0.x * Lw[jj][0] + u0.y * Lw[jj][1] + u0.z * Lw[jj][2] + u0.w * Lw[jj][3];
            float s1 = u1.x * Lw[jj][4] + u1.y * Lw[jj][5] + u1.z * Lw[jj][6] + u1.w * Lw[jj][7];
            float s2 = i0.x * Ww[jj][0] + i0.y * Ww[jj][1] + i0.z * Ww[jj][2] + i0.w * Ww[jj][3]
                     + i1.x * Ww[jj][4] + i1.y * Ww[jj][5] + i1.z * Ww[jj][6] + i1.w * Ww[jj][7];
            float s3 = i2.x * Ww[jj][8] + i2.y * Ww[jj][9] + i2.z * Ww[jj][10] + i2.w * Ww[jj][11]
                     + i3.x * Ww[jj][12] + i3.y * Ww[jj][13] + i3.z * Ww[jj][14] + i3.w * Ww[jj][15];
            nh[jj] = 0.9f * hvv[jj] + ((s0 + s1) + (s2 + s3));
        }
        *reinterpret_cast<float2*>(&out[2048 + (size_t)b * HID + j0]) =
            make_float2(nh[0], nh[1]);

        float th0 = ftanh(nh[0]);
        float th1 = ftanh(nh[1]);
#pragma unroll
        for (int k = 0; k < NOUT; ++k)
            oacc[bi][k] += th0 * Wo[0][k] + th1 * Wo[1][k];
    }

    // readout reduction: DPP wave-sum (VALU) -> LDS -> fold 4 waves
    const int wave = t >> 6, lane = t & 63;
#pragma unroll
    for (int bi = 0; bi < 8; ++bi)
#pragma unroll
        for (int k = 0; k < NOUT; ++k) {
            float s = wave_sum_dpp(oacc[bi][k]);
            if (lane == 63) ored[wave][bi * 4 + k] = s;
        }
    __syncthreads();
    if (t < 32) {
        float s = ored[0][t] + ored[1][t] + ored[2][t] + ored[3][t];
        opart[(size_t)jt * (BATCH * NOUT) + bt * 32 + t] = s;
    }
}

// Kernel 3: fold 16 j-tile partials into d_out[0:2048]
__global__ __launch_bounds__(256) void k_out(
    const float* __restrict__ opart, float* __restrict__ out) {
    const int t = blockIdx.x * 256 + threadIdx.x;  // 0..2047
    float s = 0.f;
#pragma unroll
    for (int p = 0; p < 16; ++p)
        s += opart[(size_t)p * 2048 + t];
    out[t] = s;
}

extern "C" void kernel_launch(void* const* d_in, const int* in_sizes, int n_in,
                              void* d_out, int out_size, void* d_ws, size_t ws_size,
                              hipStream_t stream) {
    const float* input = (const float*)d_in[0];   // [512,16]
    const float* hst   = (const float*)d_in[1];   // [512,8192]
    const float* W_in  = (const float*)d_in[2];   // [8192,16]
    const float* L     = (const float*)d_in[3];   // [8192,8]
    const float* R     = (const float*)d_in[4];   // [8,8192]
    const float* W_out = (const float*)d_in[5];   // [4,8192]
    float* out = (float*)d_out;                   // [2048 output | 512*8192 new_hidden]

    float* upart = (float*)d_ws;                  // 8*512*8   floats (128 KB)
    float* opart = upart + 8 * BATCH * RK;        // 16*512*4  floats (128 KB)

    k_uproj<<<dim3(8, 128), 256, 0, stream>>>(hst, R, upart);
    k_step<<<dim3(16, 64), 256, 0, stream>>>(hst, input, W_in, L, W_out, upart, out, opart);
    k_out<<<8, 256, 0, stream>>>(opart, out);
}

// Round 3
// 94.981 us; speedup vs baseline: 1.1617x; 1.0171x over previous
//
#include <hip/hip_runtime.h>

#define HID 8192
#define BATCH 512
#define NIN 16
#define RK 8
#define NOUT 4

// fast tanh via hardware exp + rcp: tanh(x) = 1 - 2/(exp(2x)+1)
__device__ __forceinline__ float ftanh(float x) {
    float e = __expf(2.0f * x);
    return 1.0f - 2.0f * __builtin_amdgcn_rcpf(e + 1.0f);
}

// wave64 sum via DPP (VALU pipe only — no LDS traffic). Result valid in lane 63.
__device__ __forceinline__ float wave_sum_dpp(float v) {
    int x;
    x = __builtin_amdgcn_update_dpp(0, __float_as_int(v), 0x111, 0xf, 0xf, true); v += __int_as_float(x);
    x = __builtin_amdgcn_update_dpp(0, __float_as_int(v), 0x112, 0xf, 0xf, true); v += __int_as_float(x);
    x = __builtin_amdgcn_update_dpp(0, __float_as_int(v), 0x114, 0xf, 0xf, true); v += __int_as_float(x);
    x = __builtin_amdgcn_update_dpp(0, __float_as_int(v), 0x118, 0xf, 0xf, true); v += __int_as_float(x);
    x = __builtin_amdgcn_update_dpp(0, __float_as_int(v), 0x142, 0xf, 0xf, true); v += __int_as_float(x);
    x = __builtin_amdgcn_update_dpp(0, __float_as_int(v), 0x143, 0xf, 0xf, true); v += __int_as_float(x);
    return v;
}

// Kernel 1: u[b,r] = sum_j tanh(h[b,j]) * R[r,j], pre-scaled by 0.1/H.
// Also zeroes d_out[0:2048] (jt==0 blocks) so k_step can atomicAdd readout
// partials directly — this replaces the former k_out dispatch. Safe because
// k_uproj fully precedes k_step in stream order and d_out is re-poisoned
// by the harness before every launch.
__global__ __launch_bounds__(256) void k_uproj(
    const float* __restrict__ h, const float* __restrict__ R,
    float* __restrict__ upart /* [8][BATCH][8] */,
    float* __restrict__ out /* d_out base */) {
    const int jt = blockIdx.x;   // 0..7
    const int bt = blockIdx.y;   // 0..127
    const int t  = threadIdx.x;  // 0..255
    const int j  = jt * 1024 + t * 4;

    if (jt == 0 && t < 16) out[bt * 16 + t] = 0.f;  // zero readout accumulators

    float4 Rr[RK];
#pragma unroll
    for (int r = 0; r < RK; ++r)
        Rr[r] = *reinterpret_cast<const float4*>(&R[r * HID + j]);

    const float sc = 0.1f / (float)HID;
    float acc[4][RK];
#pragma unroll
    for (int bi = 0; bi < 4; ++bi)
#pragma unroll
        for (int r = 0; r < RK; ++r) acc[bi][r] = 0.f;

#pragma unroll
    for (int bi = 0; bi < 4; ++bi) {
        const int b = bt * 4 + bi;
        float4 hv = *reinterpret_cast<const float4*>(&h[(size_t)b * HID + j]);
        float tx = ftanh(hv.x) * sc;
        float ty = ftanh(hv.y) * sc;
        float tz = ftanh(hv.z) * sc;
        float tw = ftanh(hv.w) * sc;
#pragma unroll
        for (int r = 0; r < RK; ++r)
            acc[bi][r] = tx * Rr[r].x + ty * Rr[r].y + tz * Rr[r].z + tw * Rr[r].w;
    }

    __shared__ float red[4][32];
    const int wave = t >> 6, lane = t & 63;
#pragma unroll
    for (int bi = 0; bi < 4; ++bi)
#pragma unroll
        for (int r = 0; r < RK; ++r) {
            float s = wave_sum_dpp(acc[bi][r]);
            if (lane == 63) red[wave][bi * RK + r] = s;
        }
    __syncthreads();
    if (t < 32) {
        float s = red[0][t] + red[1][t] + red[2][t] + red[3][t];
        const int b = bt * 4 + (t >> 3);
        upart[((size_t)jt * BATCH + b) * RK + (t & 7)] = s;
    }
}

// Kernel 2: new_h[b,j] = 0.9*h + sum_r us[b,r]*L[j,r] + sum_i (0.1*in[b,i])*W_in[j,i]
// Readout partials DPP-reduced per block, then atomicAdd'ed straight into
// d_out[0:2048] (zeroed by k_uproj) — no third kernel.
__global__ __launch_bounds__(256) void k_step(
    const float* __restrict__ h, const float* __restrict__ input,
    const float* __restrict__ W_in, const float* __restrict__ L,
    const float* __restrict__ W_out, const float* __restrict__ upart,
    float* __restrict__ out /* d_out base */) {
    const int jt = blockIdx.x;   // 0..15
    const int bt = blockIdx.y;   // 0..63
    const int t  = threadIdx.x;  // 0..255
    const int j0 = jt * 512 + t * 2;

    __shared__ __align__(16) float us_lds[64];    // [8 batches][8 r]
    __shared__ __align__(16) float in_lds[128];   // [8 batches][16 i], pre-scaled by 0.1
    __shared__ float ored[4][32];

    if (t < 64) {
        float s = 0.f;
#pragma unroll
        for (int p = 0; p < 8; ++p)
            s += upart[(size_t)p * (BATCH * RK) + bt * 64 + t];
        us_lds[t] = s;
    } else if (t < 192) {
        const int tl = t - 64;
        in_lds[tl] = input[bt * 128 + tl] * 0.1f;
    }

    // per-thread weight fragments in registers, reused across the 8-batch loop
    float Lw[2][RK], Ww[2][NIN], Wo[2][NOUT];
#pragma unroll
    for (int jj = 0; jj < 2; ++jj) {
        const int j = j0 + jj;
        float4 a = *reinterpret_cast<const float4*>(&L[j * RK]);
        float4 b4 = *reinterpret_cast<const float4*>(&L[j * RK + 4]);
        Lw[jj][0] = a.x; Lw[jj][1] = a.y; Lw[jj][2] = a.z; Lw[jj][3] = a.w;
        Lw[jj][4] = b4.x; Lw[jj][5] = b4.y; Lw[jj][6] = b4.z; Lw[jj][7] = b4.w;
#pragma unroll
        for (int q = 0; q < 4; ++q) {
            float4 w = *reinterpret_cast<const float4*>(&W_in[j * NIN + q * 4]);
            Ww[jj][q * 4 + 0] = w.x; Ww[jj][q * 4 + 1] = w.y;
            Ww[jj][q * 4 + 2] = w.z; Ww[jj][q * 4 + 3] = w.w;
        }
#pragma unroll
        for (int k = 0; k < NOUT; ++k)
            Wo[jj][k] = W_out[(size_t)k * HID + j] * (1.0f / (float)HID);
    }
    __syncthreads();

    float oacc[8][NOUT];
#pragma unroll
    for (int bi = 0; bi < 8; ++bi)
#pragma unroll
        for (int k = 0; k < NOUT; ++k) oacc[bi][k] = 0.f;

#pragma unroll
    for (int bi = 0; bi < 8; ++bi) {
        const int b = bt * 8 + bi;
        float2 hv = *reinterpret_cast<const float2*>(&h[(size_t)b * HID + j0]);
        float4 u0 = *reinterpret_cast<const float4*>(&us_lds[bi * 8]);
        float4 u1 = *reinterpret_cast<const float4*>(&us_lds[bi * 8 + 4]);
        float4 i0 = *reinterpret_cast<const float4*>(&in_lds[bi * 16]);
        float4 i1 = *reinterpret_cast<const float4*>(&in_lds[bi * 16 + 4]);
        float4 i2 = *reinterpret_cast<const float4*>(&in_lds[bi * 16 + 8]);
        float4 i3 = *reinterpret_cast<const float4*>(&in_lds[bi * 16 + 12]);

        float nh[2];
        float hvv[2] = {hv.x, hv.y};
#pragma unroll
        for (int jj = 0; jj < 2; ++jj) {
            float s0 = u0.x * Lw[jj][0] + u0.y * Lw[jj][1] + u0.z * Lw[jj][2] + u0.w * Lw[jj][3];
            float s1 = u1.x * Lw[jj][4] + u1.y * Lw[jj][5] + u1.z * Lw[jj][6] + u1.w * Lw[jj][7];
            float s2 = i0.x * Ww[jj][0] + i0.y * Ww[jj][1] + i0.z * Ww[jj][2] + i0.w * Ww[jj][3]
                     + i1.x * Ww[jj][4] + i1.y * Ww[jj][5] + i1.z * Ww[jj][6] + i1.w * Ww[jj][7];
            float s3 = i2.x * Ww[jj][8] + i2.y * Ww[jj][9] + i2.z * Ww[jj][10] + i2.w * Ww[jj][11]
                     + i3.x * Ww[jj][12] + i3.y * Ww[jj][13] + i3.z * Ww[jj][14] + i3.w * Ww[jj][15];
            nh[jj] = 0.9f * hvv[jj] + ((s0 + s1) + (s2 + s3));
        }
        *reinterpret_cast<float2*>(&out[2048 + (size_t)b * HID + j0]) =
            make_float2(nh[0], nh[1]);

        float th0 = ftanh(nh[0]);
        float th1 = ftanh(nh[1]);
#pragma unroll
        for (int k = 0; k < NOUT; ++k)
            oacc[bi][k] += th0 * Wo[0][k] + th1 * Wo[1][k];
    }

    // readout reduction: DPP wave-sum -> LDS -> fold 4 waves -> device atomicAdd
    const int wave = t >> 6, lane = t & 63;
#pragma unroll
    for (int bi = 0; bi < 8; ++bi)
#pragma unroll
        for (int k = 0; k < NOUT; ++k) {
            float s = wave_sum_dpp(oacc[bi][k]);
            if (lane == 63) ored[wave][bi * 4 + k] = s;
        }
    __syncthreads();
    if (t < 32) {
        float s = ored[0][t] + ored[1][t] + ored[2][t] + ored[3][t];
        atomicAdd(&out[bt * 32 + t], s);  // 16 adds/address over 2048 addresses
    }
}

extern "C" void kernel_launch(void* const* d_in, const int* in_sizes, int n_in,
                              void* d_out, int out_size, void* d_ws, size_t ws_size,
                              hipStream_t stream) {
    const float* input = (const float*)d_in[0];   // [512,16]
    const float* hst   = (const float*)d_in[1];   // [512,8192]
    const float* W_in  = (const float*)d_in[2];   // [8192,16]
    const float* L     = (const float*)d_in[3];   // [8192,8]
    const float* R     = (const float*)d_in[4];   // [8,8192]
    const float* W_out = (const float*)d_in[5];   // [4,8192]
    float* out = (float*)d_out;                   // [2048 output | 512*8192 new_hidden]

    float* upart = (float*)d_ws;                  // 8*512*8 floats (128 KB)

    k_uproj<<<dim3(8, 128), 256, 0, stream>>>(hst, R, upart, out);
    k_step<<<dim3(16, 64), 256, 0, stream>>>(hst, input, W_in, L, W_out, upart, out);
}